// Round 8
// baseline (51.013 us; speedup 1.0000x reference)
//
#include <hip/hip_runtime.h>

// B=524288 independent attentions over [S=10, D=6].
// out[b,q] = sum_k softmax_k(score[q,k]) * vsum[k]
// score[q,k] = x_q.(G x_k) + w.x_k  (q-constant terms cancel in softmax).
// Precompute (1-block kernel) folds log2(e) into G and w:
//   G'[d][dp] = log2e * sum_e Wq[e][d] Wk[e][dp]
//   w'[dp]    = log2e * sum_e bq[e]  Wk[e][dp]
//   wvs[d]    = sum_e Wv[e][d],  bvs = sum_e bv[e]
// ws layout (floats): [0..35] G', [36..41] w', [42..47] wvs, [48] bvs
//
// R6/R7 lesson: every LDS-staged variant is phase-locked — __syncthreads
// forces s_waitcnt vmcnt(0), draining prefetches; HBM duty ~54% across 4
// structures. R8: NO barriers, NO LDS. Rolling 2-buffer register pipeline over
// 4 elements/thread: next element's 15 float4 loads are always in flight
// while the current element computes (T14). Waves stall only inside s_waitcnt
// WITH ~15 KB outstanding -> HBM stays saturated.

#define NB 524288
#define S 10
#define D 6
#define XFL 60
#define TPB 256
#define EPT 4                        // elements per thread
#define NTHREADS (NB / EPT)          // 131072
#define NBLK (NTHREADS / TPB)        // 512 blocks -> 2 blocks/CU, 8 waves/CU
#define ESTRIDE NTHREADS             // element stride between a thread's iters

__global__ void precompute_kernel(const float* __restrict__ Wk, const float* __restrict__ bk,
                                  const float* __restrict__ Wq, const float* __restrict__ bq,
                                  const float* __restrict__ Wv, const float* __restrict__ bv,
                                  float* __restrict__ ws) {
    const float LOG2E = 1.44269504088896340736f;
    int t = threadIdx.x;
    if (t < 36) {
        int d = t / 6, dp = t % 6;
        float g = 0.f;
        for (int e = 0; e < D; ++e) g += Wq[e * D + d] * Wk[e * D + dp];
        ws[t] = g * LOG2E;
    } else if (t < 42) {
        int dp = t - 36;
        float s = 0.f;
        for (int e = 0; e < D; ++e) s += bq[e] * Wk[e * D + dp];
        ws[t] = s * LOG2E;
    } else if (t < 48) {
        int d = t - 42;
        float s = 0.f;
        for (int e = 0; e < D; ++e) s += Wv[e * D + d];
        ws[t] = s;
    } else if (t == 48) {
        float s = 0.f;
        for (int e = 0; e < D; ++e) s += bv[e];
        ws[t] = s;
    }
}

__device__ __forceinline__ float sconst(const float* __restrict__ p, int i) {
    return __int_as_float(__builtin_amdgcn_readfirstlane(__float_as_int(p[i])));
}

// Issue 15 float4 loads for one element into a register buffer.
#define LOAD_ELEM(buf, eidx)                                                 \
    {                                                                        \
        const float4* _p = (const float4*)(x + (size_t)(eidx) * XFL);        \
        _Pragma("unroll")                                                    \
        for (int _i = 0; _i < 15; ++_i) {                                    \
            float4 _v = _p[_i];                                              \
            buf[4 * _i + 0] = _v.x;                                          \
            buf[4 * _i + 1] = _v.y;                                          \
            buf[4 * _i + 2] = _v.z;                                          \
            buf[4 * _i + 3] = _v.w;                                          \
        }                                                                    \
    }

// Full per-element attention (all 10 queries). All register indices static.
#define COMPUTE_ELEM(xv, eidx)                                               \
    {                                                                        \
        float z[XFL], a[S], vs[S];                                           \
        _Pragma("unroll")                                                    \
        for (int _k = 0; _k < S; ++_k) {                                     \
            float _ak = 0.f, _vk = bvs;                                      \
            _Pragma("unroll")                                                \
            for (int _d = 0; _d < D; ++_d) {                                 \
                float _xk = xv[_k * D + _d];                                 \
                _ak += w[_d] * _xk;                                          \
                _vk += wvs[_d] * _xk;                                        \
            }                                                                \
            a[_k] = _ak; vs[_k] = _vk;                                       \
            _Pragma("unroll")                                                \
            for (int _d = 0; _d < D; ++_d) {                                 \
                float _zz = 0.f;                                             \
                _Pragma("unroll")                                            \
                for (int _dp = 0; _dp < D; ++_dp)                            \
                    _zz += G[_d * D + _dp] * xv[_k * D + _dp];               \
                z[_k * D + _d] = _zz;                                        \
            }                                                                \
        }                                                                    \
        float o[S];                                                          \
        _Pragma("unroll")                                                    \
        for (int _q = 0; _q < S; ++_q) {                                     \
            float _num = 0.f, _den = 0.f;                                    \
            _Pragma("unroll")                                                \
            for (int _k = 0; _k < S; ++_k) {                                 \
                float _s = a[_k];                                            \
                _Pragma("unroll")                                            \
                for (int _d = 0; _d < D; ++_d)                               \
                    _s += xv[_q * D + _d] * z[_k * D + _d];                  \
                float _ex = __builtin_amdgcn_exp2f(_s);                      \
                _den += _ex; _num += _ex * vs[_k];                           \
            }                                                                \
            o[_q] = _num * __builtin_amdgcn_rcpf(_den);                      \
        }                                                                    \
        float2* _op = (float2*)(out + (size_t)(eidx) * S);                   \
        _Pragma("unroll")                                                    \
        for (int _i = 0; _i < 5; ++_i)                                       \
            _op[_i] = make_float2(o[2 * _i], o[2 * _i + 1]);                 \
    }

// (256,2): 256-VGPR budget, 2 waves/SIMD. Peak live ~220 VGPR (two 60-f
// buffers + z/a/vs + o). No barriers anywhere -> no forced vmcnt drains.
__global__ __launch_bounds__(TPB, 2) void attn_kernel(const float* __restrict__ x,
                                                      const float* __restrict__ ws,
                                                      float* __restrict__ out) {
    const int g = blockIdx.x * TPB + threadIdx.x;

    // 49 wave-uniform constants pinned to SGPRs.
    float G[36], w[6], wvs[6];
    #pragma unroll
    for (int i = 0; i < 36; ++i) G[i] = sconst(ws, i);
    #pragma unroll
    for (int i = 0; i < 6; ++i) w[i] = sconst(ws, 36 + i);
    #pragma unroll
    for (int i = 0; i < 6; ++i) wvs[i] = sconst(ws, 42 + i);
    const float bvs = sconst(ws, 48);

    float bufA[XFL], bufB[XFL];

    // Rolling pipeline: loads for element i+1 are in flight during compute(i).
    LOAD_ELEM(bufA, g + 0 * ESTRIDE);
    LOAD_ELEM(bufB, g + 1 * ESTRIDE);
    COMPUTE_ELEM(bufA, g + 0 * ESTRIDE);
    LOAD_ELEM(bufA, g + 2 * ESTRIDE);
    COMPUTE_ELEM(bufB, g + 1 * ESTRIDE);
    LOAD_ELEM(bufB, g + 3 * ESTRIDE);
    COMPUTE_ELEM(bufA, g + 2 * ESTRIDE);
    COMPUTE_ELEM(bufB, g + 3 * ESTRIDE);
}

extern "C" void kernel_launch(void* const* d_in, const int* in_sizes, int n_in,
                              void* d_out, int out_size, void* d_ws, size_t ws_size,
                              hipStream_t stream) {
    const float* x  = (const float*)d_in[0];
    const float* Wk = (const float*)d_in[1];
    const float* bk = (const float*)d_in[2];   // cancels in softmax
    const float* Wq = (const float*)d_in[3];
    const float* bq = (const float*)d_in[4];
    const float* Wv = (const float*)d_in[5];
    const float* bv = (const float*)d_in[6];
    float* out = (float*)d_out;
    float* ws  = (float*)d_ws;

    precompute_kernel<<<1, 64, 0, stream>>>(Wk, bk, Wq, bq, Wv, bv, ws);
    attn_kernel<<<NBLK, TPB, 0, stream>>>(x, ws, out);
}